// Round 9
// baseline (129.174 us; speedup 1.0000x reference)
//
#include <hip/hip_runtime.h>
#include <math.h>

#define NB 8
#define NH 120
#define NW 160
#define HW (NH*NW)
#define NSEM 16
#define NCH 20
#define VR 100
#define NZ 80
#define NZP 40  // z stored as 40 u32 pairs of u16 fields (ch0)
#define ZLO 9
#define ZHI 35
#define NZS (ZHI-ZLO)
#define MD 240
#define PC 20   // proj channel stride (channel-innermost, slot == output channel, 2/3 unused)
#define YW 64   // y-window rows actually touchable by the splat (posy = d/5 in [10,70])
#define YOFF 8
#define QSCALE 1024.0f
#define QINV   0.0009765625f
#define QS0    256.0f
#define QS0INV 0.00390625f
#define PXB 60  // pixels per rottrans block (4 blocks per output row)

__device__ __forceinline__ float clamp01(float v){ return fminf(fmaxf(v, 0.0f), 1.0f); }

// Scalar-field coordinate/weight computation (exact replica of reference f32 math).
// NO arrays: runtime-indexed arrays become allocas -> AMDGPUPromoteAlloca puts
// them in 48KB LDS (rounds 5/6: occupancy 27%, 3.4M LDS bank conflicts).
struct SplatCoord {
    float wx0, wx1, wy0, wy1, wz0, wz1;
    int   xi0, xi1, yi0, yi1, zi0, zi1;
};
__device__ __forceinline__ void compute_coord(float d, int h, int w, float fl, SplatCoord& sc) {
    float X = ((float)w - 79.5f) * d / fl;
    float Z = ((float)(119 - h) - 59.5f) * d / fl;
    float pcx = X + 250.0f;
    float pcy = d;
    float pcz = Z + 88.0f;
    float posx = ((pcx/5.0f - 50.0f)/100.0f*2.0f)*50.0f + 50.0f;
    float posy = ((pcy/5.0f - 50.0f)/100.0f*2.0f)*50.0f + 50.0f;
    float posz = ((pcz/5.0f - 32.0f)/80.0f*2.0f)*40.0f + 40.0f;
    float f;
    f = floorf(posx);
    { float pi = f;        bool s = (pi > 0.0f) && (pi < 100.0f);
      sc.wx0 = s ? (1.0f - fabsf(posx - pi)) : 0.0f; sc.xi0 = s ? (int)pi : 0; }
    { float pi = f + 1.0f; bool s = (pi > 0.0f) && (pi < 100.0f);
      sc.wx1 = s ? (1.0f - fabsf(posx - pi)) : 0.0f; sc.xi1 = s ? (int)pi : 0; }
    f = floorf(posy);
    { float pi = f;        bool s = (pi > 0.0f) && (pi < 100.0f);
      sc.wy0 = s ? (1.0f - fabsf(posy - pi)) : 0.0f; sc.yi0 = s ? (int)pi : 0; }
    { float pi = f + 1.0f; bool s = (pi > 0.0f) && (pi < 100.0f);
      sc.wy1 = s ? (1.0f - fabsf(posy - pi)) : 0.0f; sc.yi1 = s ? (int)pi : 0; }
    f = floorf(posz);
    { float pi = f;        bool s = (pi > 0.0f) && (pi < 80.0f);
      sc.wz0 = s ? (1.0f - fabsf(posz - pi)) : 0.0f; sc.zi0 = s ? (int)pi : 0; }
    { float pi = f + 1.0f; bool s = (pi > 0.0f) && (pi < 80.0f);
      sc.wz1 = s ? (1.0f - fabsf(posz - pi)) : 0.0f; sc.zi1 = s ? (int)pi : 0; }
}

// ---------------- pose + affine params ----------------
__global__ void pose_k(const float* __restrict__ pose_obs,
                       const float* __restrict__ poses_last,
                       float* __restrict__ out2, float* __restrict__ out3,
                       float* __restrict__ aux) {
    int b = threadIdx.x;
    if (b >= NB) return;
    const float D2R = 0.017453292519943295f;
    float th = poses_last[b*3+2] * D2R;
    float s = sinf(th), c = cosf(th);
    float ny = poses_last[b*3+1] + pose_obs[b*3+0]*s + pose_obs[b*3+1]*c;
    float nx = poses_last[b*3+0] + pose_obs[b*3+0]*c - pose_obs[b*3+1]*s;
    float nt = poses_last[b*3+2] + pose_obs[b*3+2]*57.29577951308232f;
    nt = fmodf(nt - 180.0f, 360.0f) + 180.0f;
    nt = fmodf(nt + 180.0f, 360.0f) - 180.0f;
    out2[b*3+0] = nx; out2[b*3+1] = ny; out2[b*3+2] = nt;
    out3[b*3+0] = nx; out3[b*3+1] = ny; out3[b*3+2] = nt;
    float stt = 90.0f - nt;
    float rad = stt * D2R;
    aux[b*4+0] = cosf(rad);
    aux[b*4+1] = sinf(rad);
    aux[b*4+2] = -(nx*100.0f/5.0f - 120.0f)/120.0f;  // st_xy[:,0]
    aux[b*4+3] = -(ny*100.0f/5.0f - 120.0f)/120.0f;  // st_xy[:,1]
}

// ---------------- ch0 splat: thread per (pixel, (cx,cy)) ----------------
// vox0q: [b][zp40][yw][x] u32, two u16 z-fields (scale 256). Even z0 -> one
// atomic covers both z-corners; cx-pair lanes 4B apart share L2 lines.
__global__ void splat0_k(const float* __restrict__ obs, unsigned* __restrict__ vox0q, float fl) {
    int t = blockIdx.x*blockDim.x + threadIdx.x;
    if (t >= NB*HW*4) return;
    int k = t & 3; int pp = t >> 2;
    int b = pp / HW, p = pp % HW;
    int h = p / NW, w = p % NW;
    float d = obs[((size_t)b*NCH + 3)*HW + p];
    SplatCoord sc;
    compute_coord(d, h, w, fl, sc);
    float wxy = ((k & 1) ? sc.wx1 : sc.wx0) * ((k >> 1) ? sc.wy1 : sc.wy0);
    int   xiv = (k & 1) ? sc.xi1 : sc.xi0;
    unsigned ywi = (unsigned)(((k >> 1) ? sc.yi1 : sc.yi0) - YOFF);
    if (wxy == 0.0f || ywi >= YW) return;
    unsigned q0 = __float2uint_rn(wxy*sc.wz0*QS0);
    unsigned q1 = __float2uint_rn(wxy*sc.wz1*QS0);
    if (!(q0 | q1)) return;
    int z0 = sc.zi0, z1 = sc.zi1;
    size_t rowcol = (size_t)ywi*VR + xiv;
    if (q0 && q1 && !(z0 & 1)) {
        atomicAdd(&vox0q[((size_t)(b*NZP + (z0 >> 1))*YW*VR) + rowcol], q0 | (q1 << 16));
    } else {
        if (q0) atomicAdd(&vox0q[((size_t)(b*NZP + (z0 >> 1))*YW*VR) + rowcol],
                          (z0 & 1) ? (q0 << 16) : q0);
        if (q1) atomicAdd(&vox0q[((size_t)(b*NZP + (z1 >> 1))*YW*VR) + rowcol],
                          (z1 & 1) ? (q1 << 16) : q1);
    }
}

// ---------------- sem splat: thread per (pixel, channel-quad) ----------------
// voxS: [b][zs][yw][x][quad4] u64 = 4 x u16 fields (scale 1024). One u64 atomic
// updates 4 channels; no carry across fields (per-field sums << 2^16).
__global__ void splatS_k(const float* __restrict__ obs,
                         unsigned long long* __restrict__ voxS, float fl) {
    int t = blockIdx.x*blockDim.x + threadIdx.x;
    if (t >= NB*HW*4) return;
    int k = t & 3; int pp = t >> 2;
    int b = pp / HW, p = pp % HW;
    int h = p / NW, w = p % NW;
    const float* ob = obs + (size_t)b*NCH*HW;
    float d = ob[3*HW + p];
    SplatCoord sc;
    compute_coord(d, h, w, fl, sc);
    float f0 = ob[(4 + 4*k + 0)*HW + p];
    float f1 = ob[(4 + 4*k + 1)*HW + p];
    float f2 = ob[(4 + 4*k + 2)*HW + p];
    float f3 = ob[(4 + 4*k + 3)*HW + p];
    #pragma unroll
    for (int cz = 0; cz < 2; cz++) {
        int z = cz ? sc.zi1 : sc.zi0;
        float wzv = cz ? sc.wz1 : sc.wz0;
        if (z < ZLO || z >= ZHI) continue;
        #pragma unroll
        for (int cy = 0; cy < 2; cy++) {
            float wyz = (cy ? sc.wy1 : sc.wy0) * wzv;
            unsigned ywi = (unsigned)((cy ? sc.yi1 : sc.yi0) - YOFF);
            if (ywi >= YW) continue;
            #pragma unroll
            for (int cx = 0; cx < 2; cx++) {
                float w3 = (cx ? sc.wx1 : sc.wx0) * wyz;
                int xiv = cx ? sc.xi1 : sc.xi0;
                if (w3 == 0.0f) continue;
                unsigned q0 = __float2uint_rn(f0*w3*QSCALE);
                unsigned q1 = __float2uint_rn(f1*w3*QSCALE);
                unsigned q2 = __float2uint_rn(f2*w3*QSCALE);
                unsigned q3 = __float2uint_rn(f3*w3*QSCALE);
                unsigned long long val =
                    (unsigned long long)(q0 | (q1 << 16)) |
                    ((unsigned long long)(q2 | (q3 << 16)) << 32);
                if (val) {
                    size_t addr = (((((size_t)b*NZS + (z-ZLO))*YW + ywi)*VR + xiv)<<2) + k;
                    atomicAdd(&voxS[addr], val);
                }
            }
        }
    }
}

// ---------------- fused projections ----------------
__global__ void proj_k(const unsigned* __restrict__ vox0q, const unsigned* __restrict__ voxS,
                       float* __restrict__ proj, float* __restrict__ out0) {
    int t = blockIdx.x*blockDim.x + threadIdx.x;
    if (t < NB*VR*VR) {
        int b = t / (VR*VR), r = t % (VR*VR);
        int yy = r / VR;
        float* pb = proj + ((size_t)b*(VR*VR) + r)*PC;
        if (yy < YOFF || yy >= YOFF+YW) {
            out0[(size_t)b*(VR*VR) + r] = 0.0f;
            *reinterpret_cast<float2*>(pb) = make_float2(0.0f, 0.0f);
            return;
        }
        int rw = (yy - YOFF)*VR + (r % VR);
        const unsigned* col = vox0q + (size_t)b*NZP*(YW*VR) + rw;
        float s_all = 0.0f, s_slab = 0.0f;
        #pragma unroll
        for (int zp = 0; zp < NZP; zp++) {
            unsigned v = col[(size_t)zp*(YW*VR)];
            float v0 = rintf((float)(v & 0xFFFFu)*QS0INV);  // z = 2*zp
            float v1 = rintf((float)(v >> 16)*QS0INV);      // z = 2*zp+1
            s_all += v0 + v1;
            if (zp >= 5 && zp <= 16) s_slab += v0 + v1;     // z 10..33
            else if (zp == 4) s_slab += v1;                 // z 9
            else if (zp == 17) s_slab += v0;                // z 34
        }
        float fpm = clamp01(s_slab);  // MAP_THR = 1
        float fpe = clamp01(s_all);   // EXP_THR = 1
        out0[(size_t)b*(VR*VR) + r] = fpm;
        *reinterpret_cast<float2*>(pb) = make_float2(fpm, fpe);
        return;
    }
    int t2 = t - NB*VR*VR;
    if (t2 >= NB*VR*VR*2) return;
    int hf = t2 & 1; int rr = t2 >> 1;
    int b = rr / (VR*VR), r = rr % (VR*VR);
    int yy = r / VR;
    float* dst = proj + ((size_t)b*(VR*VR) + r)*PC + 4 + hf*8;  // 16B aligned
    if (yy < YOFF || yy >= YOFF+YW) {
        *reinterpret_cast<float4*>(dst)     = make_float4(0.0f, 0.0f, 0.0f, 0.0f);
        *reinterpret_cast<float4*>(dst + 4) = make_float4(0.0f, 0.0f, 0.0f, 0.0f);
        return;
    }
    int rw = (yy - YOFF)*VR + (r % VR);
    float a0=0.f,a1=0.f,a2=0.f,a3=0.f,a4=0.f,a5=0.f,a6=0.f,a7=0.f;
    #pragma unroll 13
    for (int zs = 0; zs < NZS; zs++) {
        const uint4 v = *reinterpret_cast<const uint4*>(
            voxS + ((((size_t)b*NZS + zs)*(YW*VR) + rw)<<3) + hf*4);
        a0 += rintf((float)(v.x & 0xFFFFu)*QINV); a1 += rintf((float)(v.x >> 16)*QINV);
        a2 += rintf((float)(v.y & 0xFFFFu)*QINV); a3 += rintf((float)(v.y >> 16)*QINV);
        a4 += rintf((float)(v.z & 0xFFFFu)*QINV); a5 += rintf((float)(v.z >> 16)*QINV);
        a6 += rintf((float)(v.w & 0xFFFFu)*QINV); a7 += rintf((float)(v.w >> 16)*QINV);
    }
    *reinterpret_cast<float4*>(dst) = make_float4(
        clamp01(a0/5.0f), clamp01(a1/5.0f), clamp01(a2/5.0f), clamp01(a3/5.0f));
    *reinterpret_cast<float4*>(dst + 4) = make_float4(
        clamp01(a4/5.0f), clamp01(a5/5.0f), clamp01(a6/5.0f), clamp01(a7/5.0f));
}

// ---------------- fused rotate+translate + max: 3-phase LDS block ----------------
// Block = 60 consecutive X of one output row. Phase1: 60 threads build tap
// tables (16 combined taps) in LDS. Phase2: 1200 (px,ch) items; consecutive
// lanes = consecutive channels of one tap pixel -> 80B contiguous chunks
// (was: 64-line scatter per wave instr). Phase3: LDS transpose -> X-coalesced
// maps read / out write. Same tap math as before (bit-identical weights).
__global__ __launch_bounds__(256) void rottrans_k(const float* __restrict__ proj,
                           const float* __restrict__ aux,
                           const float* __restrict__ maps, float* __restrict__ out1) {
    __shared__ int      s_toff[PXB*16];
    __shared__ float    s_twgt[PXB*16];
    __shared__ float    s_acc[PXB*21];   // stride 21: avoid 8-way bank conflict in phase3
    __shared__ unsigned s_live[PXB];
    int blk = blockIdx.x;
    int chunk = blk & 3;
    int rem = blk >> 2;
    int Y = rem % MD;
    int b = rem / MD;
    int X0 = chunk * PXB;
    int t = threadIdx.x;

    if (t < PXB) {
        int X = X0 + t;
        float ct = aux[b*4+0], st = aux[b*4+1];
        float tx = aux[b*4+2], ty = aux[b*4+3];
        const float step = 2.0f/239.0f;
        float Xg = (X == MD-1) ? 1.0f : (-1.0f + (float)X*step);
        float Yg = (Y == MD-1) ? 1.0f : (-1.0f + (float)Y*step);
        float x = (Xg + tx + 1.0f)*119.5f;
        float y = (Yg + ty + 1.0f)*119.5f;
        float x0 = floorf(x), y0 = floorf(y);
        unsigned live = 0;
        #pragma unroll
        for (int tt = 0; tt < 4; tt++) {
            float ix = x0 + (float)(tt & 1);
            float iy = y0 + (float)(tt >> 1);
            float wt = ((tt & 1) ? (x - x0) : (x0 + 1.0f - x)) *
                       ((tt >> 1) ? (y - y0) : (y0 + 1.0f - y));
            bool tvalid = (ix >= 0.0f) && (ix < 240.0f) && (iy >= 0.0f) && (iy < 240.0f) && (wt != 0.0f);
            float u = 0.0f, v = 0.0f;
            if (tvalid) {
                int Xi = (int)ix, Yi = (int)iy;
                float Xg2 = (Xi == MD-1) ? 1.0f : (-1.0f + (float)Xi*step);
                float Yg2 = (Yi == MD-1) ? 1.0f : (-1.0f + (float)Yi*step);
                u = ct*Xg2 - st*Yg2;
                v = st*Xg2 + ct*Yg2;
            }
            float x2 = (u + 1.0f)*119.5f;
            float y2 = (v + 1.0f)*119.5f;
            float x20 = floorf(x2), y20 = floorf(y2);
            #pragma unroll
            for (int ii = 0; ii < 4; ii++) {
                float jx = x20 + (float)(ii & 1);
                float jy = y20 + (float)(ii >> 1);
                float w2 = ((ii & 1) ? (x2 - x20) : (x20 + 1.0f - x2)) *
                           ((ii >> 1) ? (y2 - y20) : (y20 + 1.0f - y2));
                bool ivalid = tvalid && (jy >= 120.0f) && (jy < 220.0f) && (jx >= 70.0f) && (jx < 170.0f);
                int slot = tt*4 + ii;
                float w = ivalid ? wt * w2 : 0.0f;
                s_twgt[t*16 + slot] = w;
                s_toff[t*16 + slot] = ivalid ? (((int)jy - 120)*VR + ((int)jx - 70)) : 0;
                live |= (w != 0.0f) ? 1u : 0u;
            }
        }
        s_live[t] = live;
    }
    __syncthreads();

    const float* pj = proj + (size_t)b*(VR*VR)*PC;
    for (int item = t; item < PXB*PC; item += 256) {
        int px = item / PC, ch = item % PC;
        float acc = 0.0f;
        if (s_live[px]) {
            #pragma unroll
            for (int s = 0; s < 16; s++) {
                acc += s_twgt[px*16 + s] * pj[(size_t)s_toff[px*16 + s]*PC + ch];
            }
        }
        s_acc[px*21 + ch] = acc;
    }
    __syncthreads();

    size_t bbase = (size_t)b*NCH*(MD*MD) + (size_t)Y*MD + X0;
    for (int item = t; item < PXB*PC; item += 256) {
        int ch = item / PXB, px = item % PXB;
        float val = (ch == 2 || ch == 3) ? 0.0f : s_acc[px*21 + ch];
        size_t o = bbase + (size_t)ch*(MD*MD) + px;
        out1[o] = fmaxf(maps[o], val);
    }
}

extern "C" void kernel_launch(void* const* d_in, const int* in_sizes, int n_in,
                              void* d_out, int out_size, void* d_ws, size_t ws_size,
                              hipStream_t stream) {
    const float* obs        = (const float*)d_in[0];
    const float* pose_obs   = (const float*)d_in[1];
    const float* maps_last  = (const float*)d_in[2];
    const float* poses_last = (const float*)d_in[3];
    float* out  = (float*)d_out;
    float* out0 = out;                        // fp_map_pred: 8*1*100*100
    float* out1 = out + 80000;                // map_pred: 8*20*240*240
    float* out2 = out + 80000 + 9216000;      // poses
    float* out3 = out2 + 24;                  // poses (again)

    unsigned*           vox0q = (unsigned*)d_ws;                       // 8*40*64*100 u32 = 2,048,000
    unsigned long long* voxS  = (unsigned long long*)((float*)d_ws + 2048000); // 5,324,800 u64 (8B-aligned)
    float*              proj  = (float*)d_ws + 2048000 + 10649600;     // 8*100*100*20 f32
    float*              aux   = proj + 1600000;                        // 8*4

    const float FLf = (float)(80.0 / tan(39.5 * M_PI / 180.0));

    hipMemsetAsync(vox0q, 0, (size_t)(2048000 + 10649600)*4, stream);
    pose_k    <<<1, 64, 0, stream>>>(pose_obs, poses_last, out2, out3, aux);
    splat0_k  <<<(NB*HW*4 + 255)/256, 256, 0, stream>>>(obs, vox0q, FLf);
    splatS_k  <<<(NB*HW*4 + 255)/256, 256, 0, stream>>>(obs, voxS, FLf);
    proj_k    <<<(3*NB*VR*VR + 255)/256, 256, 0, stream>>>(vox0q, (const unsigned*)voxS, proj, out0);
    rottrans_k<<<NB*MD*4, 256, 0, stream>>>(proj, aux, maps_last, out1);
}